// Round 7
// baseline (407.069 us; speedup 1.0000x reference)
//
#include <hip/hip_runtime.h>
#include <hip/hip_bf16.h>

// ---------------- problem constants ----------------
#define B_    256
#define T_    250
#define NIN   700
#define NHID  512
#define NOUT  20
#define KT_N  11                 // k-tiles of 64 per segment: 704 = 11*64
#define M_TOT (B_ * T_)          // 64000

typedef float  f32x2  __attribute__((ext_vector_type(2)));
typedef float  f32x4  __attribute__((ext_vector_type(4)));
typedef float  f32x16 __attribute__((ext_vector_type(16)));
typedef int    i32x2  __attribute__((ext_vector_type(2)));
typedef int    i32x4  __attribute__((ext_vector_type(4)));
typedef int    i32x8  __attribute__((ext_vector_type(8)));

// ---------------- workspace layout ----------------
// [0, 65,536,000)   : i_in  (M_TOT x NHID bf16)
// [+, 1,441,792)    : Bpack fp8 fragment-major (4 segs)
// [+, 1,048,576)    : w_recT (512x512 f32)
// total ~68 MB
#define IIN_BYTES   ((size_t)M_TOT * NHID * 2)
#define BPACK_OFF   IIN_BYTES
#define BPACK_BYTES ((size_t)4 * KT_N * 16 * 64 * 32)
#define BPACK_WORDS (BPACK_BYTES / 4)                  // 360,448
#define WRECT_OFF   (BPACK_OFF + BPACK_BYTES)
#define BSEG        (KT_N * 16 * 512)                  // 90,112 words per B seg

// ---------------- kernel 1: pack B to fp8 fragment-major + transpose w_rec ----------------
__global__ __launch_bounds__(256) void kan_pack(
    const float* __restrict__ w_kan, const float* __restrict__ d1,
    const float* __restrict__ d2,    const float* __restrict__ d3,
    const float* __restrict__ w_rec,
    int* __restrict__ BpackW, float* __restrict__ wrecT)
{
    int idx = blockIdx.x * 256 + threadIdx.x;
    if (idx < (int)BPACK_WORDS) {
        int w   = idx;
        int c   = w >> 3;                  // 32-byte chunk index
        int jj  = (w & 7) * 4;             // byte offset within chunk
        int ln  = c & 31;
        int kh  = (c >> 5) & 1;
        int nt  = (c >> 6) & 15;
        int ks  = c >> 10;                 // seg*11 + kt
        int kt  = ks % 11;
        int seg = ks / 11;
        int n   = nt * 32 + ln;
        int kb  = kt * 64 + kh * 32 + jj;
        const float* wp = (seg == 0) ? w_kan : (seg == 1) ? d1 : (seg == 2) ? d2 : d3;
        float f0 = (kb + 0 < NIN) ? wp[(size_t)n * NIN + kb + 0] : 0.0f;
        float f1 = (kb + 1 < NIN) ? wp[(size_t)n * NIN + kb + 1] : 0.0f;
        float f2 = (kb + 2 < NIN) ? wp[(size_t)n * NIN + kb + 2] : 0.0f;
        float f3 = (kb + 3 < NIN) ? wp[(size_t)n * NIN + kb + 3] : 0.0f;
        int u = __builtin_amdgcn_cvt_pk_fp8_f32(f0, f1, 0, false);
        u     = __builtin_amdgcn_cvt_pk_fp8_f32(f2, f3, u, true);
        BpackW[w] = u;
    }
    if (idx < NHID * NHID) {
        int h  = idx & 511;
        int hp = idx >> 9;
        wrecT[(size_t)hp * NHID + h] = w_rec[(size_t)h * NHID + hp];
    }
}

// ---- pack 16 f32 -> 16 fp8 bytes (4 words) ----
__device__ __forceinline__ i32x4 pack16(const float* s) {
    i32x4 w;
    #pragma unroll
    for (int j = 0; j < 4; ++j) {
        int u = __builtin_amdgcn_cvt_pk_fp8_f32(s[4 * j + 0], s[4 * j + 1], 0, false);
        u     = __builtin_amdgcn_cvt_pk_fp8_f32(s[4 * j + 2], s[4 * j + 3], u, true);
        w[j] = u;
    }
    return w;
}

// ---- convert 16 x-values -> 4 seg fragments, store to LDS (sequential to cap regs) ----
__device__ __forceinline__ void conv_store(const float* e, int* dst) {
    *(i32x4*)(dst + 0) = pack16(e);                    // seg0: raw x
    float p1[16];
    #pragma unroll
    for (int i = 0; i < 16; ++i) p1[i] = fminf(fabsf(e[i]), 1.0f);
    *(i32x4*)(dst + 512) = pack16(p1);                 // seg1: t1
    float p2[16];
    #pragma unroll
    for (int i = 0; i < 16; ++i) p2[i] = p1[i] * p1[i];
    *(i32x4*)(dst + 1024) = pack16(p2);                // seg2: t1^2
    float p3[16];
    #pragma unroll
    for (int i = 0; i < 16; ++i) p3[i] = p2[i] * p1[i];
    *(i32x4*)(dst + 1536) = pack16(p3);                // seg3: t1^3
}

// ---------------- kernel 2: FUSED x->fp8 + GEMM, 4 independent blocks/CU ----------------
// R6 post-mortem: fusion good, but 512-thread blocks -> 1 resident block/CU ->
// all waves lockstep at the same barrier (MfmaUtil stuck at 26% = the known
// single-block ceiling). m97's 874 TF came from ~3 INDEPENDENT blocks/CU whose
// barriers interleave. This round: 256-thread blocks (4 waves), 64 rows x 256
// cols, acc[2][2]=64 VGPR, LDS 2x16KB=32KB, __launch_bounds__(256,4) -> target
// <=128 VGPR -> 4 waves/SIMD = 4 independent blocks/CU (LDS 4x32=128<=160KB).
// When one block barriers, the other three issue MFMAs. x conversion is
// duplicated x2 (two col-half blocks per row-set) -- VALU has the headroom.
__global__ __launch_bounds__(256, 4) void kan_gemm(
    const float* __restrict__ x, const int* __restrict__ Bpack,
    __bf16* __restrict__ iin)
{
    __shared__ int lds[2][4096];     // 2 x 16 KB: 2 mc-chunks x 4 segs x 512 words

    const int tid  = threadIdx.x;
    const int lane = tid & 63;
    const int wn   = tid >> 6;       // wave 0..3 : 64-col group
    const int id   = blockIdx.x;     // 0..1999
    const int bn   = id & 1;         // col half (consecutive ids share x rows)
    const int by   = id >> 1;        // 0..999 : 64-row tile
    const int l31  = lane & 31;
    const int kh   = lane >> 5;

    // conversion mapping: thread t = mcL*128 + q2*32 + r31 (r fastest -> conflict-free)
    const int r31v = tid & 31;
    const int q2   = (tid >> 5) & 3;
    const int mcL  = tid >> 7;       // 0..1
    const int xrow = by * 64 + mcL * 32 + r31v;
    const float* xr = x + (size_t)xrow * NIN;
    const int kf    = q2 * 16;
    const int wbase = mcL * 4 * 512 + (q2 & 1) * 256 + (q2 >> 1) * 128 + r31v * 4;

    f32x16 acc[2][2];
    #pragma unroll
    for (int c = 0; c < 2; ++c)
        #pragma unroll
        for (int j = 0; j < 2; ++j)
            #pragma unroll
            for (int r = 0; r < 16; ++r)
                acc[c][j][r] = 0.0f;

    // ---- prologue: load+convert kt=0 into buf 0 ----
    {
        float e[16];
        #pragma unroll
        for (int c = 0; c < 4; ++c) {
            int k = kf + c * 4;                // kt=0: always < 700
            f32x4 v = *(const f32x4*)(xr + k);
            e[c * 4 + 0] = v[0]; e[c * 4 + 1] = v[1];
            e[c * 4 + 2] = v[2]; e[c * 4 + 3] = v[3];
        }
        conv_store(e, &lds[0][wbase]);
    }
    __syncthreads();

    const int fB = bn * 8 + wn * 2;            // B col-fragment index for this wave

    int buf = 0;
    #pragma unroll 1
    for (int kt = 0; kt < KT_N - 1; ++kt) {
        // ---- issue x loads for kt+1 (pinned above MFMAs; consumed after them) ----
        f32x4 xv[4];
        #pragma unroll
        for (int c = 0; c < 4; ++c) {
            int k = (kt + 1) * 64 + kf + c * 4;
            xv[c] = (k < NIN) ? *(const f32x4*)(xr + k) : f32x4{0.f, 0.f, 0.f, 0.f};
        }
        __builtin_amdgcn_sched_barrier(0);     // keep loads above the MFMA section

        // ---- 16 MFMAs over LDS[buf] (4 segs x 2 chunks x 2 col-frags) ----
        #pragma unroll
        for (int s = 0; s < 4; ++s) {
            const int* bb = Bpack + (size_t)(kt * 16 + fB) * 512
                            + (size_t)s * BSEG + lane * 8;
            i32x8 b0 = *(const i32x8*)bb;
            i32x8 b1 = *(const i32x8*)(bb + 512);
            #pragma unroll
            for (int c = 0; c < 2; ++c) {
                const int* ab = &lds[buf][(c * 4 + s) * 512 + lane * 4];
                i32x4 lo = *(const i32x4*)ab;
                i32x4 hi = *(const i32x4*)(ab + 256);
                i32x8 A = i32x8{lo[0], lo[1], lo[2], lo[3], hi[0], hi[1], hi[2], hi[3]};
                acc[c][0] = __builtin_amdgcn_mfma_scale_f32_32x32x64_f8f6f4(
                    A, b0, acc[c][0], 0, 0, 0, 0x7f7f7f7f, 0, 0x7f7f7f7f);
                acc[c][1] = __builtin_amdgcn_mfma_scale_f32_32x32x64_f8f6f4(
                    A, b1, acc[c][1], 0, 0, 0, 0x7f7f7f7f, 0, 0x7f7f7f7f);
            }
        }

        // ---- convert kt+1 -> LDS[buf^1] (x latency hidden under MFMAs) ----
        {
            float e[16];
            #pragma unroll
            for (int c = 0; c < 4; ++c) {
                e[c * 4 + 0] = xv[c][0]; e[c * 4 + 1] = xv[c][1];
                e[c * 4 + 2] = xv[c][2]; e[c * 4 + 3] = xv[c][3];
            }
            conv_store(e, &lds[buf ^ 1][wbase]);
        }
        __syncthreads();                       // writes visible; all reads of buf done
        buf ^= 1;
    }

    // ---- final k-tile (kt = 10), no staging ----
    {
        const int kt = KT_N - 1;
        #pragma unroll
        for (int s = 0; s < 4; ++s) {
            const int* bb = Bpack + (size_t)(kt * 16 + fB) * 512
                            + (size_t)s * BSEG + lane * 8;
            i32x8 b0 = *(const i32x8*)bb;
            i32x8 b1 = *(const i32x8*)(bb + 512);
            #pragma unroll
            for (int c = 0; c < 2; ++c) {
                const int* ab = &lds[buf][(c * 4 + s) * 512 + lane * 4];
                i32x4 lo = *(const i32x4*)ab;
                i32x4 hi = *(const i32x4*)(ab + 256);
                i32x8 A = i32x8{lo[0], lo[1], lo[2], lo[3], hi[0], hi[1], hi[2], hi[3]};
                acc[c][0] = __builtin_amdgcn_mfma_scale_f32_32x32x64_f8f6f4(
                    A, b0, acc[c][0], 0, 0, 0, 0x7f7f7f7f, 0, 0x7f7f7f7f);
                acc[c][1] = __builtin_amdgcn_mfma_scale_f32_32x32x64_f8f6f4(
                    A, b1, acc[c][1], 0, 0, 0, 0x7f7f7f7f, 0, 0x7f7f7f7f);
            }
        }
    }

    // ---- epilogue: 32x32 C/D layout col=lane&31, row=(r&3)+8*(r>>2)+4*(lane>>5) ----
    #pragma unroll
    for (int c = 0; c < 2; ++c) {
        int m0 = by * 64 + c * 32 + kh * 4;
        #pragma unroll
        for (int j = 0; j < 2; ++j) {
            int col = bn * 256 + wn * 64 + j * 32 + l31;
            #pragma unroll
            for (int r = 0; r < 16; ++r) {
                int row = m0 + (r & 3) + 8 * (r >> 2);
                iin[(size_t)row * NHID + col] = (__bf16)acc[c][j][r];
            }
        }
    }
}

// ---------------- kernel 3: adaptive-LIF scan, one wave per sample, PF=25 bf16 ----------------
#define PF 25
__global__ __launch_bounds__(64) void kan_scan(
    const __bf16* __restrict__ iin, const float* __restrict__ wrecT,
    const float* __restrict__ w_out, float* __restrict__ out)
{
    const int b    = blockIdx.x;
    const int lane = threadIdx.x;
    const __bf16* basep = iin + (size_t)b * T_ * NHID + lane * 8;
    #define LOADQ(t) (*(const i32x4*)(basep + (size_t)(t) * NHID))

    i32x4 q[PF];
    #pragma unroll
    for (int d = 0; d < PF; ++d) q[d] = LOADQ(d);

    float v1[8], a1[8];
    #pragma unroll
    for (int u = 0; u < 8; ++u) { v1[u] = 0.f; a1[u] = 0.f; }
    unsigned sm = 0;
    int anyprev = 0;
    float v_out = 0.f, acco = 0.f;

    #pragma unroll 1
    for (int t0 = 0; t0 < T_; t0 += PF) {
        #pragma unroll
        for (int j = 0; j < PF; ++j) {
            const int t = t0 + j;
            float cur[8];
            #pragma unroll
            for (int w = 0; w < 4; ++w) {
                int wv = q[j][w];
                cur[2 * w]     = __builtin_bit_cast(float, wv << 16);
                cur[2 * w + 1] = __builtin_bit_cast(float, wv & 0xffff0000);
            }
            if (t + PF < T_) q[j] = LOADQ(t + PF);

            if (anyprev) {           // rare path: recurrent input from prev spikes
                #pragma unroll
                for (int u = 0; u < 8; ++u) {
                    unsigned long long mu = __ballot((sm >> u) & 1u);
                    while (mu) {
                        int jl = __ffsll(mu) - 1; mu &= mu - 1;
                        const float* wr = wrecT + (size_t)(jl * 8 + u) * NHID + lane * 8;
                        f32x4 wa = *(const f32x4*)wr;
                        f32x4 wb = *(const f32x4*)(wr + 4);
                        cur[0] += wa[0]; cur[1] += wa[1]; cur[2] += wa[2]; cur[3] += wa[3];
                        cur[4] += wb[0]; cur[5] += wb[1]; cur[6] += wb[2]; cur[7] += wb[3];
                    }
                }
            }

            unsigned nm = 0;
            #pragma unroll
            for (int u = 0; u < 8; ++u) {
                float sp = ((sm >> u) & 1u) ? 1.0f : 0.0f;
                v1[u] = 0.95f * v1[u] + 0.05f * cur[u] - sp;
                a1[u] = 0.85f * a1[u] + 0.15f * sp;
                if (v1[u] - (1.0f + 0.05f * a1[u]) > 0.0f) nm |= (1u << u);
            }

            unsigned long long anyb = __ballot(nm != 0u);
            float io = 0.0f;
            if (anyb) {              // rare path: readout current from spikes
                #pragma unroll
                for (int u = 0; u < 8; ++u) {
                    unsigned long long mu = __ballot((nm >> u) & 1u);
                    while (mu) {
                        int jl = __ffsll(mu) - 1; mu &= mu - 1;
                        int unit = jl * 8 + u;
                        if (lane < NOUT) io += w_out[(size_t)lane * NHID + unit];
                    }
                }
            }

            v_out = 0.9f * v_out + io;
            float so = (v_out - 1.0f > 0.0f) ? 1.0f : 0.0f;
            v_out -= so;
            acco += v_out;

            sm = nm;
            anyprev = (anyb != 0ull);
        }
    }

    if (lane < NOUT) out[b * NOUT + lane] = acco * (1.0f / 250.0f);
}

// ---------------- launcher ----------------
extern "C" void kernel_launch(void* const* d_in, const int* in_sizes, int n_in,
                              void* d_out, int out_size, void* d_ws, size_t ws_size,
                              hipStream_t stream)
{
    const float* x     = (const float*)d_in[0];
    const float* w_kan = (const float*)d_in[1];
    const float* d1    = (const float*)d_in[2];
    const float* d2    = (const float*)d_in[3];
    const float* d3    = (const float*)d_in[4];
    const float* w_rec = (const float*)d_in[5];
    const float* w_out = (const float*)d_in[6];
    float* out = (float*)d_out;

    char*   ws    = (char*)d_ws;
    __bf16* iin   = (__bf16*)ws;
    int*    Bpack = (int*)(ws + BPACK_OFF);
    float*  wrecT = (float*)(ws + WRECT_OFF);

    kan_pack<<<dim3((BPACK_WORDS + 255) / 256), 256, 0, stream>>>(
        w_kan, d1, d2, d3, w_rec, Bpack, wrecT);
    kan_gemm<<<dim3(2000), 256, 0, stream>>>(x, Bpack, iin);
    kan_scan<<<dim3(B_), 64, 0, stream>>>(iin, wrecT, w_out, out);
}